// Round 8
// baseline (396.341 us; speedup 1.0000x reference)
//
#include <hip/hip_runtime.h>

// Problem constants
#define BATCH 4096
#define SEQL  60
#define VOC   512
#define ADJ   184

typedef __attribute__((ext_vector_type(8))) short short8;
typedef __attribute__((ext_vector_type(4))) float f32x4;

__device__ __forceinline__ float sigm(float x) {
  return __builtin_amdgcn_rcpf(1.f + __expf(-x));
}
__device__ __forceinline__ float tanh_(float x) {
  float e = __expf(2.f * x);
  return 1.f - 2.f * __builtin_amdgcn_rcpf(e + 1.f);
}
__device__ __forceinline__ unsigned short f2bf_rne(float f) {
  unsigned int u = __float_as_uint(f);
  return (unsigned short)((u + 0x7fffu + ((u >> 16) & 1u)) >> 16);
}
__device__ __forceinline__ unsigned short f2bf(float f) {
  return (unsigned short)((__float_as_uint(f) + 0x8000u) >> 16);
}
__device__ __forceinline__ float dot4(float4 a, float4 b, float acc) {
  acc = fmaf(a.x, b.x, acc); acc = fmaf(a.y, b.y, acc);
  acc = fmaf(a.z, b.z, acc); acc = fmaf(a.w, b.w, acc);
  return acc;
}
__device__ __forceinline__ float wsumf(float v) {
  #pragma unroll
  for (int s = 32; s > 0; s >>= 1) v += __shfl_xor(v, s, 64);
  return v;
}
__device__ __forceinline__ int wsumi(int v) {
  #pragma unroll
  for (int s = 32; s > 0; s >>= 1) v += __shfl_xor(v, s, 64);
  return v;
}
__device__ __forceinline__ int wmaxi(int v) {
  #pragma unroll
  for (int s = 32; s > 0; s >>= 1) v = max(v, __shfl_xor(v, s, 64));
  return v;
}

// All kernel arguments in one struct.
struct KP {
  const int* x;
  const float *emb, *wih_f, *bif, *bhf, *wih_r, *bir, *bhr, *whh_f, *whh_r;
  const float *e_w1, *e_b1, *e_w2, *e_b2, *l_w1, *l_b1, *l_w2, *l_b2;
  const float *c_w1, *c_b1, *c_w2, *c_b2, *p_w1, *p_b1, *p_w2, *p_b2;
  const float *x_w1, *x_b1, *x_w2, *x_b2;
  const float *fp_w, *fp_b, *attn_w, *attn_b, *out_w, *out_b;
  const float *g_w1, *g_b1, *g_w2, *g_b2, *g_w3, *g_b3, *g_w4, *g_b4;
  float *G_f, *G_r;
  unsigned short* Wfrag;
  float *A, *avb, *Bp, *vb, *C1t, *c1b, *g2t, *g3t, *g4t, *cw1t;
  float *hf, *hr, *ent, *vlen, *pat, *cpx;
  int *lflag, *sflag, *p2ctr;   // done-flags (memset to 0 on stream each call)
  float* out;
};

// Shared-memory union offsets (bytes); one 15.6 KB block reused per phase.
#define SM_BYTES 15616
#define SM_HBUF  0      // lstm: 2 x 16 x 72 bf16 = 4608
#define SM_TOK   4608   // lstm: 60 x 16 u32     = 3840
#define SM_CNT   0      // stats: 4 x 512 u32    = 8192
#define SM_Q     8192   // stats: 4 x 68 u16     = 544
#define SM_FEAT  0      // head: 8 x 192 f32     = 6144
#define SM_TK    6144   // head: 8 x 64 u16      = 1024
#define SM_H1    7168   // head: 8 x 128 f32     = 4096
#define SM_H2    11264  // head: 8 x 64 f32      = 2048
#define SM_H3    13312  // head: 8 x 32 f32      = 1024
#define SM_H1C   14336  // head: 8 x 33 f32      = 1056
#define SM_LG    15392  // head: 32 f32          = 128
#define FSTR 192

// ---------------------------------------------------------------------------
// k_prep: weight-only prep, 465 blocks (unchanged from round 6).
// ---------------------------------------------------------------------------
__global__ __launch_bounds__(256) void k_prep(KP p) {
  const int bid = blockIdx.x;
  const int tid = threadIdx.x;

  if (bid < 128) {
    // G table, interleaved [v][u][gg]
    const int dir = bid >> 6;
    const int rem = bid & 63;
    const int v0 = (rem >> 2) * 32;
    const int j0 = (rem & 3) * 64;
    const float* W = dir ? p.wih_r : p.wih_f;
    const float* bi = dir ? p.bir : p.bif;
    const float* bh = dir ? p.bhr : p.bhf;
    float* G = dir ? p.G_r : p.G_f;
    const int v = v0 + (tid >> 4) * 2;
    const int j = j0 + (tid & 15) * 4;
    const int gg = j >> 6;
    const int u0 = j & 63;

    const float4* E0 = (const float4*)(p.emb + (size_t)v * 128);
    const float4* E1 = (const float4*)(p.emb + (size_t)(v + 1) * 128);
    const float4* W0 = (const float4*)(W + (size_t)j * 128);
    const float4* W1 = (const float4*)(W + (size_t)(j + 1) * 128);
    const float4* W2 = (const float4*)(W + (size_t)(j + 2) * 128);
    const float4* W3 = (const float4*)(W + (size_t)(j + 3) * 128);

    float a00 = 0.f, a01 = 0.f, a02 = 0.f, a03 = 0.f;
    float a10 = 0.f, a11 = 0.f, a12 = 0.f, a13 = 0.f;
    #pragma unroll 4
    for (int d4 = 0; d4 < 32; d4++) {
      float4 e0 = E0[d4], e1 = E1[d4];
      float4 w0 = W0[d4], w1 = W1[d4], w2 = W2[d4], w3 = W3[d4];
      a00 = dot4(e0, w0, a00); a01 = dot4(e0, w1, a01);
      a02 = dot4(e0, w2, a02); a03 = dot4(e0, w3, a03);
      a10 = dot4(e1, w0, a10); a11 = dot4(e1, w1, a11);
      a12 = dot4(e1, w2, a12); a13 = dot4(e1, w3, a13);
    }
    float b0v = bi[j] + bh[j], b1v = bi[j + 1] + bh[j + 1];
    float b2v = bi[j + 2] + bh[j + 2], b3v = bi[j + 3] + bh[j + 3];
    float* g0 = G + (size_t)v * 256 + u0 * 4 + gg;
    g0[0]  = a00 + b0v; g0[4]  = a01 + b1v;
    g0[8]  = a02 + b2v; g0[12] = a03 + b3v;
    float* g1 = g0 + 256;
    g1[0]  = a10 + b0v; g1[4]  = a11 + b1v;
    g1[8]  = a12 + b2v; g1[12] = a13 + b3v;
  } else if (bid < 144) {
    // w_hh bf16 MFMA B-fragments
    const int id = (bid - 128) * 256 + tid;
    const int lane = id & 63;
    const int fc = id >> 6;
    const int c = fc & 1;
    const int gg = (fc >> 1) & 3;
    const int w = (fc >> 3) & 3;
    const int dir = fc >> 5;
    const float* whh = dir ? p.whh_r : p.whh_f;
    const int n = gg * 64 + w * 16 + (lane & 15);
    const int kb = c * 32 + (lane >> 4) * 8;
    unsigned short* o = p.Wfrag + (size_t)id * 8;
    #pragma unroll
    for (int j = 0; j < 8; j++) o[j] = f2bf_rne(whh[n * 64 + kb + j]);
  } else if (bid < 272) {
    // A = g_w1 · out_w (128 x 184), avb fold
    const int i = bid - 144;
    const int j = tid;
    const float* g1r = p.g_w1 + (size_t)i * ADJ;
    if (j < ADJ) {
      float a0 = 0.f, a1 = 0.f, a2 = 0.f, a3 = 0.f;
      for (int k = 0; k < ADJ; k += 4) {
        a0 = fmaf(g1r[k],     p.out_w[(size_t)(k)     * ADJ + j], a0);
        a1 = fmaf(g1r[k + 1], p.out_w[(size_t)(k + 1) * ADJ + j], a1);
        a2 = fmaf(g1r[k + 2], p.out_w[(size_t)(k + 2) * ADJ + j], a2);
        a3 = fmaf(g1r[k + 3], p.out_w[(size_t)(k + 3) * ADJ + j], a3);
      }
      p.A[(size_t)i * ADJ + j] = (a0 + a1) + (a2 + a3);
    } else if (j == ADJ) {
      float a0 = 0.f;
      for (int k = 0; k < ADJ; k++) a0 = fmaf(g1r[k], p.out_b[k], a0);
      p.avb[i] = a0 + p.g_b1[i];
    }
  } else if (bid < 456) {
    // B = wv · fp_w (184 x 180), vb fold
    const int k = bid - 272;
    const int j = tid;
    const float* wvr = p.attn_w + (size_t)(2 * ADJ + k) * ADJ;
    if (j < 180) {
      float a0 = 0.f, a1 = 0.f, a2 = 0.f, a3 = 0.f;
      for (int m = 0; m < ADJ; m += 4) {
        a0 = fmaf(wvr[m],     p.fp_w[(size_t)(m)     * 180 + j], a0);
        a1 = fmaf(wvr[m + 1], p.fp_w[(size_t)(m + 1) * 180 + j], a1);
        a2 = fmaf(wvr[m + 2], p.fp_w[(size_t)(m + 2) * 180 + j], a2);
        a3 = fmaf(wvr[m + 3], p.fp_w[(size_t)(m + 3) * 180 + j], a3);
      }
      p.Bp[(size_t)k * 180 + j] = (a0 + a1) + (a2 + a3);
    } else if (j == 180) {
      float a0 = 0.f;
      for (int m = 0; m < ADJ; m++) a0 = fmaf(wvr[m], p.fp_b[m], a0);
      p.vb[k] = a0 + p.attn_b[2 * ADJ + k];
    }
  } else if (bid == 456) {
    // transposes for the head
    for (int i = tid; i < 64 * 128; i += 256) {
      int o = i >> 7, k = i & 127;
      p.g2t[k * 64 + o] = p.g_w2[i];
    }
    for (int i = tid; i < 32 * 64; i += 256) {
      int o = i >> 6, k = i & 63;
      p.g3t[k * 32 + o] = p.g_w3[i];
    }
    if (tid < 128) {
      int o = tid >> 5, k = tid & 31;
      p.g4t[k * 4 + o] = p.g_w4[tid];
    }
  } else {
    // transpose c_w1 (32x512) -> cw1t (512x32), row 0 zeroed
    const int base = (bid - 457) * 2048;
    for (int i = tid; i < 2048; i += 256) {
      int idx = base + i;
      int o = idx >> 9, k = idx & 511;
      p.cw1t[k * 32 + o] = k ? p.c_w1[o * 512 + k] : 0.f;
    }
  }
}

// ---------------------------------------------------------------------------
// LSTM block (16 rows, one direction). bid in [0,512).
// ---------------------------------------------------------------------------
#define LSTM_STEP(T, CUR, NXT)                                                 \
  {                                                                            \
    const unsigned short* hb = hbuf + ((T) & 1) * (16 * 72);                   \
    short8 a0 = *(const short8*)(hb + ln * 72 + kg * 8);                       \
    short8 a1 = *(const short8*)(hb + ln * 72 + 32 + kg * 8);                  \
    if ((T) < 59) {                                                            \
      int tsn = dir ? (58 - (T)) : ((T) + 1);                                  \
      uint4 of4 = *(const uint4*)(tokoff + tsn * 16 + kg * 4);                 \
      NXT[0] = *(const float4*)(Gb + of4.x + ub);                              \
      NXT[1] = *(const float4*)(Gb + of4.y + ub);                              \
      NXT[2] = *(const float4*)(Gb + of4.z + ub);                              \
      NXT[3] = *(const float4*)(Gb + of4.w + ub);                              \
    }                                                                          \
    f32x4 z0 = {0.f, 0.f, 0.f, 0.f};                                           \
    f32x4 acc0 = z0, acc1 = z0, acc2 = z0, acc3 = z0;                          \
    acc0 = __builtin_amdgcn_mfma_f32_16x16x32_bf16(a0, bfr[0][0], acc0, 0, 0, 0); \
    acc1 = __builtin_amdgcn_mfma_f32_16x16x32_bf16(a0, bfr[1][0], acc1, 0, 0, 0); \
    acc2 = __builtin_amdgcn_mfma_f32_16x16x32_bf16(a0, bfr[2][0], acc2, 0, 0, 0); \
    acc3 = __builtin_amdgcn_mfma_f32_16x16x32_bf16(a0, bfr[3][0], acc3, 0, 0, 0); \
    acc0 = __builtin_amdgcn_mfma_f32_16x16x32_bf16(a1, bfr[0][1], acc0, 0, 0, 0); \
    acc1 = __builtin_amdgcn_mfma_f32_16x16x32_bf16(a1, bfr[1][1], acc1, 0, 0, 0); \
    acc2 = __builtin_amdgcn_mfma_f32_16x16x32_bf16(a1, bfr[2][1], acc2, 0, 0, 0); \
    acc3 = __builtin_amdgcn_mfma_f32_16x16x32_bf16(a1, bfr[3][1], acc3, 0, 0, 0); \
    unsigned short* hw = hbuf + (((T) + 1) & 1) * (16 * 72);                   \
    _Pragma("unroll")                                                          \
    for (int r = 0; r < 4; r++) {                                              \
      float gi = acc0[r] + CUR[r].x;                                           \
      float gf = acc1[r] + CUR[r].y;                                           \
      float gc = acc2[r] + CUR[r].z;                                           \
      float go = acc3[r] + CUR[r].w;                                           \
      float cn = sigm(gf) * cst[r] + sigm(gi) * tanh_(gc);                     \
      cst[r] = cn;                                                             \
      float h = sigm(go) * tanh_(cn);                                          \
      hw[(kg * 4 + r) * 72 + u] = f2bf(h);                                     \
      if ((T) == 59) ho[(size_t)(b0 + kg * 4 + r) * 64 + u] = h;               \
    }                                                                          \
    __syncthreads();                                                           \
  }

__device__ void lstm_block(int bid, int tid, const KP& p, char* smem) {
  unsigned short* hbuf = (unsigned short*)(smem + SM_HBUF);
  unsigned int* tokoff = (unsigned int*)(smem + SM_TOK);
  const int lane = tid & 63;
  const int w = tid >> 6;
  const int dir = bid >> 8;
  const int blk = bid & 255;
  const int b0 = blk << 4;
  const float* G = dir ? p.G_r : p.G_f;
  const char* Gb = (const char*)G;
  float* ho = dir ? p.hr : p.hf;

  for (int i = tid; i < 960; i += 256) {
    int r = i / 60, t = i - r * 60;
    tokoff[t * 16 + r] = ((unsigned int)p.x[(size_t)(b0 + r) * 60 + t]) << 10;
  }
  for (int i = tid; i < 16 * 72; i += 256) hbuf[i] = 0;

  short8 bfr[4][2];
  #pragma unroll
  for (int gg = 0; gg < 4; gg++)
    #pragma unroll
    for (int c = 0; c < 2; c++) {
      int idx = (((dir * 4 + w) * 4 + gg) * 2 + c) * 64 + lane;
      bfr[gg][c] = *(const short8*)(p.Wfrag + (size_t)idx * 8);
    }

  const int kg = lane >> 4;
  const int ln = lane & 15;
  const int u = w * 16 + ln;
  const unsigned int ub = (unsigned int)u * 16;
  float cst[4] = {0.f, 0.f, 0.f, 0.f};
  float4 gvA[4], gvB[4];

  __syncthreads();

  {
    int ts0 = dir ? 59 : 0;
    uint4 of4 = *(const uint4*)(tokoff + ts0 * 16 + kg * 4);
    gvA[0] = *(const float4*)(Gb + of4.x + ub);
    gvA[1] = *(const float4*)(Gb + of4.y + ub);
    gvA[2] = *(const float4*)(Gb + of4.z + ub);
    gvA[3] = *(const float4*)(Gb + of4.w + ub);
  }

  #pragma unroll 1
  for (int tt = 0; tt < 30; tt++) {
    const int t0 = tt * 2, t1 = tt * 2 + 1;
    LSTM_STEP(t0, gvA, gvB)
    LSTM_STEP(t1, gvB, gvA)
  }
  // release: h rows for this block are globally visible
  __threadfence();
  __syncthreads();
  if (tid == 0) atomicExch(&p.lflag[bid], 1);
}

// ---------------------------------------------------------------------------
// prep2 unit (block): C1t = (A·B)^T column i, c1b fold. i in [0,128).
// ---------------------------------------------------------------------------
__device__ void prep2_block(int i, int j, const KP& p) {
  const float* Ar = p.A + (size_t)i * ADJ;
  if (j < 180) {
    float a0 = 0.f, a1 = 0.f, a2 = 0.f, a3 = 0.f;
    for (int k = 0; k < ADJ; k += 4) {
      a0 = fmaf(Ar[k],     p.Bp[(size_t)(k)     * 180 + j], a0);
      a1 = fmaf(Ar[k + 1], p.Bp[(size_t)(k + 1) * 180 + j], a1);
      a2 = fmaf(Ar[k + 2], p.Bp[(size_t)(k + 2) * 180 + j], a2);
      a3 = fmaf(Ar[k + 3], p.Bp[(size_t)(k + 3) * 180 + j], a3);
    }
    p.C1t[(size_t)j * 128 + i] = (a0 + a1) + (a2 + a3);
  } else if (j == 180) {
    float a0 = 0.f;
    for (int k = 0; k < ADJ; k++) a0 = fmaf(Ar[k], p.vb[k], a0);
    p.c1b[i] = a0 + p.avb[i];
  }
  __threadfence();
  __syncthreads();
  if (j == 0) atomicAdd(p.p2ctr, 1);
}

// ---------------------------------------------------------------------------
// stats block: 4 rows, wave-per-row. s in [0,1024).
// ---------------------------------------------------------------------------
__device__ void stats_block(int s, int tid, const KP& p, char* smem) {
  unsigned int* cntb = (unsigned int*)(smem + SM_CNT);
  unsigned short* qb = (unsigned short*)(smem + SM_Q);
  const int lane = tid & 63;
  const int wid = tid >> 6;
  const int row = s * 4 + wid;
  unsigned int* cr = cntb + wid * 512;
  unsigned short* qr = qb + wid * 68;

  for (int i = lane; i < 512; i += 64) cr[i] = 0u;
  qr[lane] = 0;
  if (lane < 4) qr[64 + lane] = 0;
  int v = (lane < 60) ? p.x[row * 60 + lane] : 0;
  bool act = (v != 0);
  unsigned long long amask = __ballot(act);
  int n = __popcll(amask);
  __syncthreads();
  if (act) {
    int pos = __popcll(amask & ((1ull << lane) - 1ull));
    qr[pos] = (unsigned short)v;
    atomicAdd(&cr[v], 1u);
  }
  __syncthreads();

  float vlenf = (float)(n >= 1 ? n : 1);
  float inv = 1.f / vlenf;

  float ent = 0.f; int distinct = 0;
  #pragma unroll
  for (int j = 0; j < 8; j++) {
    unsigned int c = cr[lane + j * 64];
    if (c) {
      distinct++;
      float pr = (float)c * inv;
      ent -= pr * __logf(pr + 1e-8f);
    }
  }
  ent = wsumf(ent);
  distinct = wsumi(distinct);

  int a = qr[lane], b = qr[lane + 1], c2 = qr[lane + 2];
  bool v1 = (lane + 1 < n);
  bool v2 = (lane + 2 < n);
  int rep  = __popcll(__ballot(v1 && (a == b)));
  int incs = __popcll(__ballot(v1 && (b > a)));
  int decs = __popcll(__ballot(v1 && (b < a)));
  int per2 = __popcll(__ballot(v2 && (a == c2)));

  int prev = (lane > 0) ? (int)qr[lane - 1] : -1;
  bool isst = (lane < n) && (lane == 0 || a != prev);
  unsigned long long smask = __ballot(isst);
  int len = 0;
  if (isst) {
    unsigned long long hi = (lane < 63) ? (smask >> (lane + 1)) : 0ull;
    int next = hi ? (lane + __ffsll((unsigned long long)hi)) : n;
    len = next - lane;
  }
  int maxrun = wmaxi(len);

  int code = v1 ? (a * VOC + b) : -1;
  int unique = v1 ? 1 : 0;
  #pragma unroll 1
  for (int j = 0; j < 58; j++) {
    int cj = __shfl(code, j, 64);
    if (j < lane && cj == code) unique = 0;
  }
  int dc = __popcll(__ballot(unique != 0));

  int wl = n >> 1; if (wl > 5) wl = 5;
  float local = 0.f;
  if (wl >= 2) {
    bool pv = (lane + wl <= n);
    int u = 0;
    if (pv) {
      int t0 = qr[lane], t1 = qr[lane + 1], t2 = qr[lane + 2];
      int t3 = qr[lane + 3], t4 = qr[lane + 4];
      u = 1;
      u += (t1 != t0);
      if (wl >= 3) u += (int)((t2 != t1) && (t2 != t0));
      if (wl >= 4) u += (int)((t3 != t2) && (t3 != t1) && (t3 != t0));
      if (wl >= 5) u += (int)((t4 != t3) && (t4 != t2) && (t4 != t1) && (t4 != t0));
    }
    int usum = wsumi(u);
    int denw = n - wl + 1; if (denw < 1) denw = 1;
    local = (float)usum / (float)wl / (float)denw;
  }

  float den1 = (float)((n - 1) >= 1 ? (n - 1) : 1);
  float repeat = (float)rep / den1;
  float per = (n >= 4) ? (float)per2 / (float)((n - 2) >= 1 ? (n - 2) : 1) : 0.f;
  float entz = (n > 1) ? ent : 0.f;
  float z = (n > 1) ? 1.f : 0.f;

  if (lane == 0) {
    p.ent[row] = entz;
    p.vlen[row] = (float)n;
    p.pat[row * 6 + 0] = repeat * z;
    p.pat[row * 6 + 1] = (float)incs / den1 * z;
    p.pat[row * 6 + 2] = (float)decs / den1 * z;
    p.pat[row * 6 + 3] = per * z;
    p.pat[row * 6 + 4] = (float)distinct * inv * z;
    p.pat[row * 6 + 5] = (float)maxrun * inv * z;
    p.cpx[row * 4 + 0] = (float)dc / den1 * z;
    p.cpx[row * 4 + 1] = entz / __logf((float)(n >= 2 ? n : 2)) * z;
    p.cpx[row * 4 + 2] = local * z;
    p.cpx[row * 4 + 3] = (1.f - repeat) * z;
  }
  __threadfence();
  __syncthreads();
  if (tid == 0) atomicExch(&p.sflag[s], 1);
}

// ---------------------------------------------------------------------------
// Head block (8 rows). hb in [0,512). Spins (s_sleep-throttled) on its
// producers' flags first — provably deadlock-free (see launch comment).
// ---------------------------------------------------------------------------
__device__ void head_block(int hb, int tid, const KP& p, char* smem) {
  if (tid == 0) {
    while (atomicAdd(p.p2ctr, 0) < 128) __builtin_amdgcn_s_sleep(16);
    while (atomicAdd(&p.lflag[hb >> 1], 0) == 0) __builtin_amdgcn_s_sleep(16);
    while (atomicAdd(&p.lflag[256 + (hb >> 1)], 0) == 0) __builtin_amdgcn_s_sleep(16);
    while (atomicAdd(&p.sflag[hb * 2], 0) == 0) __builtin_amdgcn_s_sleep(16);
    while (atomicAdd(&p.sflag[hb * 2 + 1], 0) == 0) __builtin_amdgcn_s_sleep(16);
    __threadfence();
  }
  __syncthreads();

  float* feat = (float*)(smem + SM_FEAT);
  unsigned short* tk = (unsigned short*)(smem + SM_TK);
  float* h1 = (float*)(smem + SM_H1);
  float* h2 = (float*)(smem + SM_H2);
  float* h3 = (float*)(smem + SM_H3);
  float* h1c = (float*)(smem + SM_H1C);
  float* lg = (float*)(smem + SM_LG);
  const int b0 = hb * 8;

  if (tid < 128) {
    int r = tid >> 4, c = tid & 15;
    float4 vv = ((const float4*)(p.hf + (size_t)(b0 + r) * 64))[c];
    *(float4*)(feat + r * FSTR + c * 4) = vv;
  } else {
    int t = tid - 128;
    int r = t >> 4, c = t & 15;
    float4 vv = ((const float4*)(p.hr + (size_t)(b0 + r) * 64))[c];
    *(float4*)(feat + r * FSTR + 64 + c * 4) = vv;
  }
  for (int i = tid; i < 480; i += 256) {
    int r = i / 60, t = i - r * 60;
    tk[r * 64 + t] = (unsigned short)p.x[(size_t)(b0 + r) * 60 + t];
  }
  __syncthreads();
  // c-MLP layer 1 sparse gather
  {
    int o = tid & 31, r = tid >> 5;
    const unsigned short* tkr = tk + r * 64;
    float a0 = 0.f, a1 = 0.f, a2 = 0.f, a3 = 0.f;
    #pragma unroll 5
    for (int t = 0; t < 60; t += 4) {
      int t0 = tkr[t], t1 = tkr[t + 1], t2 = tkr[t + 2], t3 = tkr[t + 3];
      a0 += p.cw1t[t0 * 32 + o];
      a1 += p.cw1t[t1 * 32 + o];
      a2 += p.cw1t[t2 * 32 + o];
      a3 += p.cw1t[t3 * 32 + o];
    }
    float invv = __builtin_amdgcn_rcpf(fmaxf(p.vlen[b0 + r], 1.f));
    h1c[r * 33 + o] = fmaxf(((a0 + a1) + (a2 + a3)) * invv + p.c_b1[o], 0.f);
  }
  __syncthreads();
  if (tid < 32) {
    const int m = tid & 3, r = tid >> 2, b = b0 + r;
    float tt[24];
    if (m == 0) {
      float ein = p.ent[b] * 0.25f;
      #pragma unroll
      for (int o = 0; o < 16; o++) tt[o] = fmaxf(p.e_w1[o] * ein + p.e_b1[o], 0.f);
      #pragma unroll
      for (int o = 0; o < 8; o++) {
        float a = p.e_b2[o];
        #pragma unroll
        for (int k = 0; k < 16; k++) a = fmaf(p.e_w2[o * 16 + k], tt[k], a);
        feat[r * FSTR + 128 + o] = a;
      }
    } else if (m == 1) {
      float lin = p.vlen[b] * (1.f / 60.f);
      #pragma unroll
      for (int o = 0; o < 16; o++) tt[o] = fmaxf(p.l_w1[o] * lin + p.l_b1[o], 0.f);
      #pragma unroll
      for (int o = 0; o < 8; o++) {
        float a = p.l_b2[o];
        #pragma unroll
        for (int k = 0; k < 16; k++) a = fmaf(p.l_w2[o * 16 + k], tt[k], a);
        feat[r * FSTR + 136 + o] = a;
      }
    } else if (m == 2) {
      float pin[6];
      #pragma unroll
      for (int k = 0; k < 6; k++) pin[k] = p.pat[b * 6 + k];
      #pragma unroll
      for (int o = 0; o < 24; o++) {
        float a = p.p_b1[o];
        #pragma unroll
        for (int k = 0; k < 6; k++) a = fmaf(p.p_w1[o * 6 + k], pin[k], a);
        tt[o] = fmaxf(a, 0.f);
      }
      #pragma unroll
      for (int o = 0; o < 12; o++) {
        float a = p.p_b2[o];
        #pragma unroll
        for (int k = 0; k < 24; k++) a = fmaf(p.p_w2[o * 24 + k], tt[k], a);
        feat[r * FSTR + 160 + o] = a;
      }
    } else {
      float xin[4];
      #pragma unroll
      for (int k = 0; k < 4; k++) xin[k] = p.cpx[b * 4 + k];
      #pragma unroll
      for (int o = 0; o < 16; o++) {
        float a = p.x_b1[o];
        #pragma unroll
        for (int k = 0; k < 4; k++) a = fmaf(p.x_w1[o * 4 + k], xin[k], a);
        tt[o] = fmaxf(a, 0.f);
      }
      #pragma unroll
      for (int o = 0; o < 8; o++) {
        float a = p.x_b2[o];
        #pragma unroll
        for (int k = 0; k < 16; k++) a = fmaf(p.x_w2[o * 16 + k], tt[k], a);
        feat[r * FSTR + 172 + o] = a;
      }
    }
  } else if (tid >= 64 && tid < 192) {
    int t = tid - 64;
    int r = t >> 4, o = t & 15;
    float a = p.c_b2[o];
    const float* hh = h1c + r * 33;
    #pragma unroll
    for (int k = 0; k < 32; k++) a = fmaf(p.c_w2[o * 32 + k], hh[k], a);
    feat[r * FSTR + 144 + o] = a;
  }
  __syncthreads();

  // L1: 180 -> 128 relu
  {
    const int o = tid & 127, rg = tid >> 7;
    const float* f0p = feat + (rg * 4 + 0) * FSTR;
    const float* f1p = feat + (rg * 4 + 1) * FSTR;
    const float* f2p = feat + (rg * 4 + 2) * FSTR;
    const float* f3p = feat + (rg * 4 + 3) * FSTR;
    float a0 = 0.f, a1 = 0.f, a2 = 0.f, a3 = 0.f;
    #pragma unroll 3
    for (int k4 = 0; k4 < 45; k4++) {
      float w0 = p.C1t[(size_t)(k4 * 4 + 0) * 128 + o];
      float w1 = p.C1t[(size_t)(k4 * 4 + 1) * 128 + o];
      float w2 = p.C1t[(size_t)(k4 * 4 + 2) * 128 + o];
      float w3 = p.C1t[(size_t)(k4 * 4 + 3) * 128 + o];
      float4 f0 = *(const float4*)(f0p + k4 * 4);
      float4 f1 = *(const float4*)(f1p + k4 * 4);
      float4 f2 = *(const float4*)(f2p + k4 * 4);
      float4 f3 = *(const float4*)(f3p + k4 * 4);
      a0 = fmaf(w0, f0.x, a0); a0 = fmaf(w1, f0.y, a0);
      a0 = fmaf(w2, f0.z, a0); a0 = fmaf(w3, f0.w, a0);
      a1 = fmaf(w0, f1.x, a1); a1 = fmaf(w1, f1.y, a1);
      a1 = fmaf(w2, f1.z, a1); a1 = fmaf(w3, f1.w, a1);
      a2 = fmaf(w0, f2.x, a2); a2 = fmaf(w1, f2.y, a2);
      a2 = fmaf(w2, f2.z, a2); a2 = fmaf(w3, f2.w, a2);
      a3 = fmaf(w0, f3.x, a3); a3 = fmaf(w1, f3.y, a3);
      a3 = fmaf(w2, f3.z, a3); a3 = fmaf(w3, f3.w, a3);
    }
    float bb = p.c1b[o];
    h1[(rg * 4 + 0) * 128 + o] = fmaxf(a0 + bb, 0.f);
    h1[(rg * 4 + 1) * 128 + o] = fmaxf(a1 + bb, 0.f);
    h1[(rg * 4 + 2) * 128 + o] = fmaxf(a2 + bb, 0.f);
    h1[(rg * 4 + 3) * 128 + o] = fmaxf(a3 + bb, 0.f);
  }
  __syncthreads();
  // L2: 128 -> 64 relu
  {
    const int o = tid & 63, rg = tid >> 6;
    const float* f0p = h1 + (rg * 2 + 0) * 128;
    const float* f1p = h1 + (rg * 2 + 1) * 128;
    float a0 = 0.f, a1 = 0.f;
    #pragma unroll 4
    for (int k4 = 0; k4 < 32; k4++) {
      float w0 = p.g2t[(k4 * 4 + 0) * 64 + o];
      float w1 = p.g2t[(k4 * 4 + 1) * 64 + o];
      float w2 = p.g2t[(k4 * 4 + 2) * 64 + o];
      float w3 = p.g2t[(k4 * 4 + 3) * 64 + o];
      float4 f0 = *(const float4*)(f0p + k4 * 4);
      float4 f1 = *(const float4*)(f1p + k4 * 4);
      a0 = fmaf(w0, f0.x, a0); a0 = fmaf(w1, f0.y, a0);
      a0 = fmaf(w2, f0.z, a0); a0 = fmaf(w3, f0.w, a0);
      a1 = fmaf(w0, f1.x, a1); a1 = fmaf(w1, f1.y, a1);
      a1 = fmaf(w2, f1.z, a1); a1 = fmaf(w3, f1.w, a1);
    }
    float bb = p.g_b2[o];
    h2[(rg * 2 + 0) * 64 + o] = fmaxf(a0 + bb, 0.f);
    h2[(rg * 2 + 1) * 64 + o] = fmaxf(a1 + bb, 0.f);
  }
  __syncthreads();
  // L3: 64 -> 32 relu
  {
    const int o = tid & 31, rg = tid >> 5;
    const float* fp = h2 + rg * 64;
    float a = 0.f;
    #pragma unroll 4
    for (int k4 = 0; k4 < 16; k4++) {
      float w0 = p.g3t[(k4 * 4 + 0) * 32 + o];
      float w1 = p.g3t[(k4 * 4 + 1) * 32 + o];
      float w2 = p.g3t[(k4 * 4 + 2) * 32 + o];
      float w3 = p.g3t[(k4 * 4 + 3) * 32 + o];
      float4 f0 = *(const float4*)(fp + k4 * 4);
      a = fmaf(w0, f0.x, a); a = fmaf(w1, f0.y, a);
      a = fmaf(w2, f0.z, a); a = fmaf(w3, f0.w, a);
    }
    h3[rg * 32 + o] = fmaxf(a + p.g_b3[o], 0.f);
  }
  __syncthreads();
  // L4: 32 -> 4 logits
  if (tid < 32) {
    int r = tid >> 2, o = tid & 3;
    const float* hh = h3 + r * 32;
    float a = p.g_b4[o];
    #pragma unroll
    for (int k = 0; k < 32; k++) a = fmaf(p.g4t[k * 4 + o], hh[k], a);
    lg[tid] = a;
  }
  __syncthreads();
  if (tid < 8) {
    float l0 = lg[tid * 4 + 0], l1 = lg[tid * 4 + 1];
    float l2 = lg[tid * 4 + 2], l3 = lg[tid * 4 + 3];
    float m = fmaxf(fmaxf(l0, l1), fmaxf(l2, l3));
    float e0 = __expf(l0 - m), e1 = __expf(l1 - m);
    float e2 = __expf(l2 - m), e3 = __expf(l3 - m);
    float is = __builtin_amdgcn_rcpf(e0 + e1 + e2 + e3);
    float4 o4; o4.x = e0 * is; o4.y = e1 * is; o4.z = e2 * is; o4.w = e3 * is;
    *(float4*)(p.out + (size_t)(b0 + tid) * 4) = o4;
  }
}

// ---------------------------------------------------------------------------
// k_main: ONE regular launch, flag-synced internally (no cooperative API).
//   [0,512)      LSTM (producers; set lflag[bid] on completion)
//   [512,640)    prep2 (increment p2ctr)
//   [640,1664)   stats (set sflag)
//   [1664,2176)  head (spin on 2 lflags + 2 sflags + p2ctr, then compute)
// Deadlock-free: only head blocks (512) spin; resident capacity >= 1024
// blocks (LDS 15.6KB -> 10/CU, VGPRs ~64 -> 8/CU), so a non-spinning block
// is always resident and retiring -> dispatch always progresses, regardless
// of dispatch order.
// ---------------------------------------------------------------------------
__global__ __launch_bounds__(256) void k_main(KP p) {
  __shared__ __align__(16) char smem[SM_BYTES];
  const int bid = blockIdx.x;
  const int tid = threadIdx.x;
  if (bid < 512) {
    lstm_block(bid, tid, p, smem);
  } else if (bid < 640) {
    prep2_block(bid - 512, tid, p);
  } else if (bid < 1664) {
    stats_block(bid - 640, tid, p, smem);
  } else {
    head_block(bid - 1664, tid, p, smem);
  }
}

// ---------------------------------------------------------------------------
extern "C" void kernel_launch(void* const* d_in, const int* in_sizes, int n_in,
                              void* d_out, int out_size, void* d_ws, size_t ws_size,
                              hipStream_t stream) {
  KP p;
  p.x     = (const int*)d_in[0];
  p.emb   = (const float*)d_in[1];
  p.wih_f = (const float*)d_in[2];
  p.whh_f = (const float*)d_in[3];
  p.bif   = (const float*)d_in[4];
  p.bhf   = (const float*)d_in[5];
  p.wih_r = (const float*)d_in[6];
  p.whh_r = (const float*)d_in[7];
  p.bir   = (const float*)d_in[8];
  p.bhr   = (const float*)d_in[9];
  p.e_w1 = (const float*)d_in[10]; p.e_b1 = (const float*)d_in[11];
  p.e_w2 = (const float*)d_in[12]; p.e_b2 = (const float*)d_in[13];
  p.l_w1 = (const float*)d_in[14]; p.l_b1 = (const float*)d_in[15];
  p.l_w2 = (const float*)d_in[16]; p.l_b2 = (const float*)d_in[17];
  p.c_w1 = (const float*)d_in[18]; p.c_b1 = (const float*)d_in[19];
  p.c_w2 = (const float*)d_in[20]; p.c_b2 = (const float*)d_in[21];
  p.p_w1 = (const float*)d_in[22]; p.p_b1 = (const float*)d_in[23];
  p.p_w2 = (const float*)d_in[24]; p.p_b2 = (const float*)d_in[25];
  p.x_w1 = (const float*)d_in[26]; p.x_b1 = (const float*)d_in[27];
  p.x_w2 = (const float*)d_in[28]; p.x_b2 = (const float*)d_in[29];
  p.fp_w = (const float*)d_in[30]; p.fp_b = (const float*)d_in[31];
  p.attn_w = (const float*)d_in[32]; p.attn_b = (const float*)d_in[33];
  p.out_w = (const float*)d_in[34]; p.out_b = (const float*)d_in[35];
  p.g_w1 = (const float*)d_in[36]; p.g_b1 = (const float*)d_in[37];
  p.g_w2 = (const float*)d_in[38]; p.g_b2 = (const float*)d_in[39];
  p.g_w3 = (const float*)d_in[40]; p.g_b3 = (const float*)d_in[41];
  p.g_w4 = (const float*)d_in[42]; p.g_b4 = (const float*)d_in[43];

  float* ws = (float*)d_ws;
  p.G_f  = ws;                            // 512*256
  p.G_r  = p.G_f + 512 * 256;
  p.hf   = p.G_r + 512 * 256;             // B*64
  p.hr   = p.hf + BATCH * 64;
  p.ent  = p.hr + BATCH * 64;             // B
  p.vlen = p.ent + BATCH;
  p.pat  = p.vlen + BATCH;                // B*6
  p.cpx  = p.pat + BATCH * 6;             // B*4
  p.A    = p.cpx + BATCH * 4;             // 128*184
  p.avb  = p.A + 128 * ADJ;               // 128
  p.Bp   = p.avb + 128;                   // 184*180
  p.vb   = p.Bp + ADJ * 180;              // 184
  p.C1t  = p.vb + ADJ;                    // 180*128
  p.c1b  = p.C1t + 180 * 128;             // 128
  p.g2t  = p.c1b + 128;                   // 128*64
  p.g3t  = p.g2t + 128 * 64;              // 64*32
  p.g4t  = p.g3t + 64 * 32;               // 32*4
  p.cw1t = p.g4t + 32 * 4;                // 512*32
  p.Wfrag = (unsigned short*)(p.cw1t + 512 * 32);  // 32768 bf16
  int* flags = (int*)(p.Wfrag + 32768);
  p.lflag = flags;                        // 512
  p.sflag = flags + 512;                  // 1024
  p.p2ctr = flags + 1536;                 // 1
  p.out  = (float*)d_out;

  // zero the flag region (ws is re-poisoned to 0xAA before every call)
  hipMemsetAsync((void*)flags, 0, 1540 * sizeof(int), stream);
  k_prep<<<dim3(465), dim3(256), 0, stream>>>(p);
  k_main<<<dim3(2176), dim3(256), 0, stream>>>(p);
}

// Round 9
// 247.590 us; speedup vs baseline: 1.6008x; 1.6008x over previous
//
#include <hip/hip_runtime.h>

// Problem constants
#define BATCH 4096
#define SEQL  60
#define VOC   512
#define ADJ   184

typedef __attribute__((ext_vector_type(8))) short short8;
typedef __attribute__((ext_vector_type(4))) float f32x4;

__device__ __forceinline__ float sigm(float x) {
  return __builtin_amdgcn_rcpf(1.f + __expf(-x));
}
__device__ __forceinline__ float tanh_(float x) {
  float e = __expf(2.f * x);
  return 1.f - 2.f * __builtin_amdgcn_rcpf(e + 1.f);
}
__device__ __forceinline__ unsigned short f2bf_rne(float f) {
  unsigned int u = __float_as_uint(f);
  return (unsigned short)((u + 0x7fffu + ((u >> 16) & 1u)) >> 16);
}
__device__ __forceinline__ unsigned short f2bf(float f) {
  // round-half-up: 2 VALU ops; <=1/2 ulp extra error on |h|<1
  return (unsigned short)((__float_as_uint(f) + 0x8000u) >> 16);
}
__device__ __forceinline__ float dot4(float4 a, float4 b, float acc) {
  acc = fmaf(a.x, b.x, acc); acc = fmaf(a.y, b.y, acc);
  acc = fmaf(a.z, b.z, acc); acc = fmaf(a.w, b.w, acc);
  return acc;
}
__device__ __forceinline__ float wsumf(float v) {
  #pragma unroll
  for (int s = 32; s > 0; s >>= 1) v += __shfl_xor(v, s, 64);
  return v;
}
__device__ __forceinline__ int wsumi(int v) {
  #pragma unroll
  for (int s = 32; s > 0; s >>= 1) v += __shfl_xor(v, s, 64);
  return v;
}
__device__ __forceinline__ int wmaxi(int v) {
  #pragma unroll
  for (int s = 32; s > 0; s >>= 1) v = max(v, __shfl_xor(v, s, 64));
  return v;
}

// LDS-only barrier: waits DS ops (h exchange) but leaves global (G prefetch)
// loads in flight across the barrier. Cross-wave data is LDS-only here, so
// lgkmcnt(0)+s_barrier is a correct release/acquire for hbuf.
#define LSTM_BAR()                                            \
  do {                                                        \
    asm volatile("s_waitcnt lgkmcnt(0)" ::: "memory");        \
    __builtin_amdgcn_s_barrier();                             \
  } while (0)

// ---------------------------------------------------------------------------
// k_prep: weight-only prep (everything with no dependence on x):
//   [0,128)    G table (interleaved [v][u][4 gates], both dirs)
//   [128,144)  Wfrag (bf16 MFMA B-operand fragments of w_hh)
//   [144,272)  A = g_w1·out_w (+ avb bias fold)
//   [272,456)  B = wv·fp_w    (+ vb bias fold)
//   [456]      transposes g_w2t/g_w3t/g_w4t
//   [457,465)  transpose c_w1 -> c_w1t[512][32], row 0 zeroed (token-0 mask)
// ---------------------------------------------------------------------------
__global__ __launch_bounds__(256) void k_prep(
    const float* __restrict__ emb,
    const float* __restrict__ wih_f, const float* __restrict__ bif, const float* __restrict__ bhf,
    const float* __restrict__ wih_r, const float* __restrict__ bir, const float* __restrict__ bhr,
    const float* __restrict__ whh_f, const float* __restrict__ whh_r,
    const float* __restrict__ g_w1, const float* __restrict__ g_b1,
    const float* __restrict__ out_w, const float* __restrict__ out_b,
    const float* __restrict__ attn_w, const float* __restrict__ attn_b,
    const float* __restrict__ fp_w, const float* __restrict__ fp_b,
    const float* __restrict__ g_w2, const float* __restrict__ g_w3,
    const float* __restrict__ g_w4, const float* __restrict__ c_w1,
    float* __restrict__ G_f, float* __restrict__ G_r,
    unsigned short* __restrict__ Wfrag,
    float* __restrict__ A, float* __restrict__ avb,
    float* __restrict__ Bp, float* __restrict__ vb,
    float* __restrict__ g_w2t, float* __restrict__ g_w3t, float* __restrict__ g_w4t,
    float* __restrict__ c_w1t) {
  const int bid = blockIdx.x;
  const int tid = threadIdx.x;

  if (bid < 128) {
    const int dir = bid >> 6;
    const int rem = bid & 63;
    const int v0 = (rem >> 2) * 32;
    const int j0 = (rem & 3) * 64;
    const float* W = dir ? wih_r : wih_f;
    const float* bi = dir ? bir : bif;
    const float* bh = dir ? bhr : bhf;
    float* G = dir ? G_r : G_f;
    const int v = v0 + (tid >> 4) * 2;
    const int j = j0 + (tid & 15) * 4;
    const int gg = j >> 6;
    const int u0 = j & 63;

    const float4* E0 = (const float4*)(emb + (size_t)v * 128);
    const float4* E1 = (const float4*)(emb + (size_t)(v + 1) * 128);
    const float4* W0 = (const float4*)(W + (size_t)j * 128);
    const float4* W1 = (const float4*)(W + (size_t)(j + 1) * 128);
    const float4* W2 = (const float4*)(W + (size_t)(j + 2) * 128);
    const float4* W3 = (const float4*)(W + (size_t)(j + 3) * 128);

    float a00 = 0.f, a01 = 0.f, a02 = 0.f, a03 = 0.f;
    float a10 = 0.f, a11 = 0.f, a12 = 0.f, a13 = 0.f;
    #pragma unroll 4
    for (int d4 = 0; d4 < 32; d4++) {
      float4 e0 = E0[d4], e1 = E1[d4];
      float4 w0 = W0[d4], w1 = W1[d4], w2 = W2[d4], w3 = W3[d4];
      a00 = dot4(e0, w0, a00); a01 = dot4(e0, w1, a01);
      a02 = dot4(e0, w2, a02); a03 = dot4(e0, w3, a03);
      a10 = dot4(e1, w0, a10); a11 = dot4(e1, w1, a11);
      a12 = dot4(e1, w2, a12); a13 = dot4(e1, w3, a13);
    }
    float b0v = bi[j] + bh[j], b1v = bi[j + 1] + bh[j + 1];
    float b2v = bi[j + 2] + bh[j + 2], b3v = bi[j + 3] + bh[j + 3];
    float* g0 = G + (size_t)v * 256 + u0 * 4 + gg;
    g0[0]  = a00 + b0v; g0[4]  = a01 + b1v;
    g0[8]  = a02 + b2v; g0[12] = a03 + b3v;
    float* g1 = g0 + 256;
    g1[0]  = a10 + b0v; g1[4]  = a11 + b1v;
    g1[8]  = a12 + b2v; g1[12] = a13 + b3v;
  } else if (bid < 144) {
    const int id = (bid - 128) * 256 + tid;
    const int lane = id & 63;
    const int fc = id >> 6;
    const int c = fc & 1;
    const int gg = (fc >> 1) & 3;
    const int w = (fc >> 3) & 3;
    const int dir = fc >> 5;
    const float* whh = dir ? whh_r : whh_f;
    const int n = gg * 64 + w * 16 + (lane & 15);
    const int kb = c * 32 + (lane >> 4) * 8;
    unsigned short* o = Wfrag + (size_t)id * 8;
    #pragma unroll
    for (int j = 0; j < 8; j++) o[j] = f2bf_rne(whh[n * 64 + kb + j]);
  } else if (bid < 272) {
    const int i = bid - 144;
    const int j = tid;
    const float* g1r = g_w1 + (size_t)i * ADJ;
    if (j < ADJ) {
      float a0 = 0.f, a1 = 0.f, a2 = 0.f, a3 = 0.f;
      for (int k = 0; k < ADJ; k += 4) {
        a0 = fmaf(g1r[k],     out_w[(size_t)(k)     * ADJ + j], a0);
        a1 = fmaf(g1r[k + 1], out_w[(size_t)(k + 1) * ADJ + j], a1);
        a2 = fmaf(g1r[k + 2], out_w[(size_t)(k + 2) * ADJ + j], a2);
        a3 = fmaf(g1r[k + 3], out_w[(size_t)(k + 3) * ADJ + j], a3);
      }
      A[(size_t)i * ADJ + j] = (a0 + a1) + (a2 + a3);
    } else if (j == ADJ) {
      float a0 = 0.f;
      for (int k = 0; k < ADJ; k++) a0 = fmaf(g1r[k], out_b[k], a0);
      avb[i] = a0 + g_b1[i];
    }
  } else if (bid < 456) {
    const int k = bid - 272;
    const int j = tid;
    const float* wvr = attn_w + (size_t)(2 * ADJ + k) * ADJ;
    if (j < 180) {
      float a0 = 0.f, a1 = 0.f, a2 = 0.f, a3 = 0.f;
      for (int m = 0; m < ADJ; m += 4) {
        a0 = fmaf(wvr[m],     fp_w[(size_t)(m)     * 180 + j], a0);
        a1 = fmaf(wvr[m + 1], fp_w[(size_t)(m + 1) * 180 + j], a1);
        a2 = fmaf(wvr[m + 2], fp_w[(size_t)(m + 2) * 180 + j], a2);
        a3 = fmaf(wvr[m + 3], fp_w[(size_t)(m + 3) * 180 + j], a3);
      }
      Bp[(size_t)k * 180 + j] = (a0 + a1) + (a2 + a3);
    } else if (j == 180) {
      float a0 = 0.f;
      for (int m = 0; m < ADJ; m++) a0 = fmaf(wvr[m], fp_b[m], a0);
      vb[k] = a0 + attn_b[2 * ADJ + k];
    }
  } else if (bid == 456) {
    for (int i = tid; i < 64 * 128; i += 256) {
      int o = i >> 7, k = i & 127;
      g_w2t[k * 64 + o] = g_w2[i];
    }
    for (int i = tid; i < 32 * 64; i += 256) {
      int o = i >> 6, k = i & 63;
      g_w3t[k * 32 + o] = g_w3[i];
    }
    if (tid < 128) {
      int o = tid >> 5, k = tid & 31;
      g_w4t[k * 4 + o] = g_w4[tid];
    }
  } else {
    const int base = (bid - 457) * 2048;
    for (int i = tid; i < 2048; i += 256) {
      int idx = base + i;
      int o = idx >> 9, k = idx & 511;
      c_w1t[k * 32 + o] = k ? c_w1[o * 512 + k] : 0.f;
    }
  }
}

// ---------------------------------------------------------------------------
// k_main: fused launch (round-6 proven structure).
//   [0,512)      MFMA LSTM recurrence (LDS-only per-step barrier)
//   [512,1536)   per-row sequence statistics (wave-per-row)
//   [1536,1664)  prep2: C1t = (A·B)^T, c1b fold
// ---------------------------------------------------------------------------
#define LSTM_STEP(T, CUR, NXT)                                                 \
  {                                                                            \
    const unsigned short* hb = hbuf[(T) & 1];                                  \
    short8 a0 = *(const short8*)(hb + ln * 72 + kg * 8);                       \
    short8 a1 = *(const short8*)(hb + ln * 72 + 32 + kg * 8);                  \
    if ((T) < 59) {                                                            \
      int tsn = dir ? (58 - (T)) : ((T) + 1);                                  \
      uint4 of4 = *(const uint4*)(tokoff + tsn * 16 + kg * 4);                 \
      NXT[0] = *(const float4*)(Gb + of4.x + ub);                              \
      NXT[1] = *(const float4*)(Gb + of4.y + ub);                              \
      NXT[2] = *(const float4*)(Gb + of4.z + ub);                              \
      NXT[3] = *(const float4*)(Gb + of4.w + ub);                              \
    }                                                                          \
    f32x4 z0 = {0.f, 0.f, 0.f, 0.f};                                           \
    f32x4 acc0 = z0, acc1 = z0, acc2 = z0, acc3 = z0;                          \
    acc0 = __builtin_amdgcn_mfma_f32_16x16x32_bf16(a0, bfr[0][0], acc0, 0, 0, 0); \
    acc1 = __builtin_amdgcn_mfma_f32_16x16x32_bf16(a0, bfr[1][0], acc1, 0, 0, 0); \
    acc2 = __builtin_amdgcn_mfma_f32_16x16x32_bf16(a0, bfr[2][0], acc2, 0, 0, 0); \
    acc3 = __builtin_amdgcn_mfma_f32_16x16x32_bf16(a0, bfr[3][0], acc3, 0, 0, 0); \
    acc0 = __builtin_amdgcn_mfma_f32_16x16x32_bf16(a1, bfr[0][1], acc0, 0, 0, 0); \
    acc1 = __builtin_amdgcn_mfma_f32_16x16x32_bf16(a1, bfr[1][1], acc1, 0, 0, 0); \
    acc2 = __builtin_amdgcn_mfma_f32_16x16x32_bf16(a1, bfr[2][1], acc2, 0, 0, 0); \
    acc3 = __builtin_amdgcn_mfma_f32_16x16x32_bf16(a1, bfr[3][1], acc3, 0, 0, 0); \
    unsigned short* hw = hbuf[((T) + 1) & 1];                                  \
    _Pragma("unroll")                                                          \
    for (int r = 0; r < 4; r++) {                                              \
      float gi = acc0[r] + CUR[r].x;                                           \
      float gf = acc1[r] + CUR[r].y;                                           \
      float gc = acc2[r] + CUR[r].z;                                           \
      float go = acc3[r] + CUR[r].w;                                           \
      float cn = sigm(gf) * cst[r] + sigm(gi) * tanh_(gc);                     \
      cst[r] = cn;                                                             \
      float h = sigm(go) * tanh_(cn);                                          \
      hw[(kg * 4 + r) * 72 + u] = f2bf(h);                                     \
      if ((T) == 59) ho[(size_t)(b0 + kg * 4 + r) * 64 + u] = h;               \
    }                                                                          \
    LSTM_BAR();                                                                \
  }

__global__ __launch_bounds__(256) void k_main(
    const int* __restrict__ x,
    const float* __restrict__ G_f, const float* __restrict__ G_r,
    const unsigned short* __restrict__ Wfrag,
    const float* __restrict__ A, const float* __restrict__ avb,
    const float* __restrict__ Bp, const float* __restrict__ vb,
    float* __restrict__ C1t, float* __restrict__ c1b,
    float* __restrict__ hf_o, float* __restrict__ hr_o,
    float* __restrict__ ent_o, float* __restrict__ vlen_o,
    float* __restrict__ pat_o, float* __restrict__ cpx_o) {
  __shared__ __align__(16) unsigned short hbuf[2][16 * 72];
  __shared__ __align__(16) unsigned int tokoff[60 * 16];
  __shared__ unsigned int cnt[4][512];
  __shared__ unsigned short q[4][68];
  const int bid = blockIdx.x;
  const int tid = threadIdx.x;

  if (bid < 512) {
    // ======================= LSTM recurrence =======================
    const int lane = tid & 63;
    const int w = tid >> 6;
    const int dir = bid >> 8;
    const int blk = bid & 255;
    const int b0 = blk << 4;
    const float* G = dir ? G_r : G_f;
    const char* Gb = (const char*)G;
    float* ho = dir ? hr_o : hf_o;

    for (int i = tid; i < 960; i += 256) {
      int r = i / 60, t = i - r * 60;
      tokoff[t * 16 + r] = ((unsigned int)x[(size_t)(b0 + r) * 60 + t]) << 10;
    }
    for (int i = tid; i < 16 * 72; i += 256) hbuf[0][i] = 0;

    short8 bfr[4][2];
    #pragma unroll
    for (int gg = 0; gg < 4; gg++)
      #pragma unroll
      for (int c = 0; c < 2; c++) {
        int idx = (((dir * 4 + w) * 4 + gg) * 2 + c) * 64 + lane;
        bfr[gg][c] = *(const short8*)(Wfrag + (size_t)idx * 8);
      }

    const int kg = lane >> 4;
    const int ln = lane & 15;
    const int u = w * 16 + ln;
    const unsigned int ub = (unsigned int)u * 16;
    float cst[4] = {0.f, 0.f, 0.f, 0.f};
    float4 gvA[4], gvB[4];

    __syncthreads();

    {
      int ts0 = dir ? 59 : 0;
      uint4 of4 = *(const uint4*)(tokoff + ts0 * 16 + kg * 4);
      gvA[0] = *(const float4*)(Gb + of4.x + ub);
      gvA[1] = *(const float4*)(Gb + of4.y + ub);
      gvA[2] = *(const float4*)(Gb + of4.z + ub);
      gvA[3] = *(const float4*)(Gb + of4.w + ub);
    }

    #pragma unroll 1
    for (int tt = 0; tt < 30; tt++) {
      const int t0 = tt * 2, t1 = tt * 2 + 1;
      LSTM_STEP(t0, gvA, gvB)
      LSTM_STEP(t1, gvB, gvA)
    }
  } else if (bid < 1536) {
    // ======================= sequence statistics =======================
    const int lane = tid & 63;
    const int wid = tid >> 6;
    const int row = (bid - 512) * 4 + wid;
    unsigned int* cr = cnt[wid];
    unsigned short* qr = q[wid];

    for (int i = lane; i < 512; i += 64) cr[i] = 0u;
    qr[lane] = 0;
    if (lane < 4) qr[64 + lane] = 0;
    int v = (lane < 60) ? x[row * 60 + lane] : 0;
    bool act = (v != 0);
    unsigned long long amask = __ballot(act);
    int n = __popcll(amask);
    __syncthreads();
    if (act) {
      int pos = __popcll(amask & ((1ull << lane) - 1ull));
      qr[pos] = (unsigned short)v;
      atomicAdd(&cr[v], 1u);
    }
    __syncthreads();

    float vlenf = (float)(n >= 1 ? n : 1);
    float inv = 1.f / vlenf;

    float ent = 0.f; int distinct = 0;
    #pragma unroll
    for (int j = 0; j < 8; j++) {
      unsigned int c = cr[lane + j * 64];
      if (c) {
        distinct++;
        float p = (float)c * inv;
        ent -= p * __logf(p + 1e-8f);
      }
    }
    ent = wsumf(ent);
    distinct = wsumi(distinct);

    int a = qr[lane], b = qr[lane + 1], c2 = qr[lane + 2];
    bool v1 = (lane + 1 < n);
    bool v2 = (lane + 2 < n);
    int rep  = __popcll(__ballot(v1 && (a == b)));
    int incs = __popcll(__ballot(v1 && (b > a)));
    int decs = __popcll(__ballot(v1 && (b < a)));
    int per2 = __popcll(__ballot(v2 && (a == c2)));

    int prev = (lane > 0) ? (int)qr[lane - 1] : -1;
    bool isst = (lane < n) && (lane == 0 || a != prev);
    unsigned long long smask = __ballot(isst);
    int len = 0;
    if (isst) {
      unsigned long long hi = (lane < 63) ? (smask >> (lane + 1)) : 0ull;
      int next = hi ? (lane + __ffsll((unsigned long long)hi)) : n;
      len = next - lane;
    }
    int maxrun = wmaxi(len);

    int code = v1 ? (a * VOC + b) : -1;
    int unique = v1 ? 1 : 0;
    #pragma unroll 1
    for (int j = 0; j < 58; j++) {
      int cj = __shfl(code, j, 64);
      if (j < lane && cj == code) unique = 0;
    }
    int dc = __popcll(__ballot(unique != 0));

    int wl = n >> 1; if (wl > 5) wl = 5;
    float local = 0.f;
    if (wl >= 2) {
      bool pv = (lane + wl <= n);
      int u = 0;
      if (pv) {
        int t0 = qr[lane], t1 = qr[lane + 1], t2 = qr[lane + 2];
        int t3 = qr[lane + 3], t4 = qr[lane + 4];
        u = 1;
        u += (t1 != t0);
        if (wl >= 3) u += (int)((t2 != t1) && (t2 != t0));
        if (wl >= 4) u += (int)((t3 != t2) && (t3 != t1) && (t3 != t0));
        if (wl >= 5) u += (int)((t4 != t3) && (t4 != t2) && (t4 != t1) && (t4 != t0));
      }
      int usum = wsumi(u);
      int denw = n - wl + 1; if (denw < 1) denw = 1;
      local = (float)usum / (float)wl / (float)denw;
    }

    float den1 = (float)((n - 1) >= 1 ? (n - 1) : 1);
    float repeat = (float)rep / den1;
    float per = (n >= 4) ? (float)per2 / (float)((n - 2) >= 1 ? (n - 2) : 1) : 0.f;
    float entz = (n > 1) ? ent : 0.f;
    float z = (n > 1) ? 1.f : 0.f;

    if (lane == 0) {
      ent_o[row] = entz;
      vlen_o[row] = (float)n;
      pat_o[row * 6 + 0] = repeat * z;
      pat_o[row * 6 + 1] = (float)incs / den1 * z;
      pat_o[row * 6 + 2] = (float)decs / den1 * z;
      pat_o[row * 6 + 3] = per * z;
      pat_o[row * 6 + 4] = (float)distinct * inv * z;
      pat_o[row * 6 + 5] = (float)maxrun * inv * z;
      cpx_o[row * 4 + 0] = (float)dc / den1 * z;
      cpx_o[row * 4 + 1] = entz / __logf((float)(n >= 2 ? n : 2)) * z;
      cpx_o[row * 4 + 2] = local * z;
      cpx_o[row * 4 + 3] = (1.f - repeat) * z;
    }
  } else {
    // ======================= prep2 (head collapse) =======================
    const int i = bid - 1536, j = tid;
    const float* Ar = A + (size_t)i * ADJ;
    if (j < 180) {
      float a0 = 0.f, a1 = 0.f, a2 = 0.f, a3 = 0.f;
      for (int k = 0; k < ADJ; k += 4) {
        a0 = fmaf(Ar[k],     Bp[(size_t)(k)     * 180 + j], a0);
        a1 = fmaf(Ar[k + 1], Bp[(size_t)(k + 1) * 180 + j], a1);
        a2 = fmaf(Ar[k + 2], Bp[(size_t)(k + 2) * 180 + j], a2);
        a3 = fmaf(Ar[k + 3], Bp[(size_t)(k + 3) * 180 + j], a3);
      }
      C1t[(size_t)j * 128 + i] = (a0 + a1) + (a2 + a3);
    } else if (j == 180) {
      float a0 = 0.f;
      for (int k = 0; k < ADJ; k++) a0 = fmaf(Ar[k], vb[k], a0);
      c1b[i] = a0 + avb[i];
    }
  }
}

// ---------------------------------------------------------------------------
// k_head: feature assembly + collapsed head (round-6 proven).
// 512 blocks x 256 threads, 8 rows/block.
// ---------------------------------------------------------------------------
#define FSTR 192

__global__ __launch_bounds__(256) void k_head(
    const int* __restrict__ x,
    const float* __restrict__ hf, const float* __restrict__ hr,
    const float* __restrict__ ent, const float* __restrict__ vlen,
    const float* __restrict__ pat, const float* __restrict__ cpx,
    const float* __restrict__ e_w1, const float* __restrict__ e_b1,
    const float* __restrict__ e_w2, const float* __restrict__ e_b2,
    const float* __restrict__ l_w1, const float* __restrict__ l_b1,
    const float* __restrict__ l_w2, const float* __restrict__ l_b2,
    const float* __restrict__ c_w1t, const float* __restrict__ c_b1,
    const float* __restrict__ c_w2, const float* __restrict__ c_b2,
    const float* __restrict__ p_w1, const float* __restrict__ p_b1,
    const float* __restrict__ p_w2, const float* __restrict__ p_b2,
    const float* __restrict__ x_w1, const float* __restrict__ x_b1,
    const float* __restrict__ x_w2, const float* __restrict__ x_b2,
    const float* __restrict__ C1t, const float* __restrict__ c1b,
    const float* __restrict__ g_w2t, const float* __restrict__ g_b2,
    const float* __restrict__ g_w3t, const float* __restrict__ g_b3,
    const float* __restrict__ g_w4t, const float* __restrict__ g_b4,
    float* __restrict__ out) {
  __shared__ float feat[8 * FSTR];
  __shared__ unsigned short tk[8 * 64];
  __shared__ float h1[8 * 128];
  __shared__ float h2[8 * 64];
  __shared__ float h3[8 * 32];
  __shared__ float h1c[8 * 33];
  __shared__ float lg[32];
  const int tid = threadIdx.x;
  const int b0 = blockIdx.x * 8;

  if (tid < 128) {
    int r = tid >> 4, c = tid & 15;
    float4 vv = ((const float4*)(hf + (size_t)(b0 + r) * 64))[c];
    *(float4*)(feat + r * FSTR + c * 4) = vv;
  } else {
    int t = tid - 128;
    int r = t >> 4, c = t & 15;
    float4 vv = ((const float4*)(hr + (size_t)(b0 + r) * 64))[c];
    *(float4*)(feat + r * FSTR + 64 + c * 4) = vv;
  }
  for (int i = tid; i < 480; i += 256) {
    int r = i / 60, t = i - r * 60;
    tk[r * 64 + t] = (unsigned short)x[(size_t)(b0 + r) * 60 + t];
  }
  __syncthreads();
  {
    int o = tid & 31, r = tid >> 5;
    const unsigned short* tkr = tk + r * 64;
    float a0 = 0.f, a1 = 0.f, a2 = 0.f, a3 = 0.f;
    #pragma unroll 5
    for (int t = 0; t < 60; t += 4) {
      int t0 = tkr[t], t1 = tkr[t + 1], t2 = tkr[t + 2], t3 = tkr[t + 3];
      a0 += c_w1t[t0 * 32 + o];
      a1 += c_w1t[t1 * 32 + o];
      a2 += c_w1t[t2 * 32 + o];
      a3 += c_w1t[t3 * 32 + o];
    }
    float invv = __builtin_amdgcn_rcpf(fmaxf(vlen[b0 + r], 1.f));
    h1c[r * 33 + o] = fmaxf(((a0 + a1) + (a2 + a3)) * invv + c_b1[o], 0.f);
  }
  __syncthreads();
  if (tid < 32) {
    const int m = tid & 3, r = tid >> 2, b = b0 + r;
    float tt[24];
    if (m == 0) {
      float ein = ent[b] * 0.25f;
      #pragma unroll
      for (int o = 0; o < 16; o++) tt[o] = fmaxf(e_w1[o] * ein + e_b1[o], 0.f);
      #pragma unroll
      for (int o = 0; o < 8; o++) {
        float a = e_b2[o];
        #pragma unroll
        for (int k = 0; k < 16; k++) a = fmaf(e_w2[o * 16 + k], tt[k], a);
        feat[r * FSTR + 128 + o] = a;
      }
    } else if (m == 1) {
      float lin = vlen[b] * (1.f / 60.f);
      #pragma unroll
      for (int o = 0; o < 16; o++) tt[o] = fmaxf(l_w1[o] * lin + l_b1[o], 0.f);
      #pragma unroll
      for (int o = 0; o < 8; o++) {
        float a = l_b2[o];
        #pragma unroll
        for (int k = 0; k < 16; k++) a = fmaf(l_w2[o * 16 + k], tt[k], a);
        feat[r * FSTR + 136 + o] = a;
      }
    } else if (m == 2) {
      float pin[6];
      #pragma unroll
      for (int k = 0; k < 6; k++) pin[k] = pat[b * 6 + k];
      #pragma unroll
      for (int o = 0; o < 24; o++) {
        float a = p_b1[o];
        #pragma unroll
        for (int k = 0; k < 6; k++) a = fmaf(p_w1[o * 6 + k], pin[k], a);
        tt[o] = fmaxf(a, 0.f);
      }
      #pragma unroll
      for (int o = 0; o < 12; o++) {
        float a = p_b2[o];
        #pragma unroll
        for (int k = 0; k < 24; k++) a = fmaf(p_w2[o * 24 + k], tt[k], a);
        feat[r * FSTR + 160 + o] = a;
      }
    } else {
      float xin[4];
      #pragma unroll
      for (int k = 0; k < 4; k++) xin[k] = cpx[b * 4 + k];
      #pragma unroll
      for (int o = 0; o < 16; o++) {
        float a = x_b1[o];
        #pragma unroll
        for (int k = 0; k < 4; k++) a = fmaf(x_w1[o * 4 + k], xin[k], a);
        tt[o] = fmaxf(a, 0.f);
      }
      #pragma unroll
      for (int o = 0; o < 8; o++) {
        float a = x_b2[o];
        #pragma unroll
        for (int k = 0; k < 16; k++) a = fmaf(x_w2[o * 16 + k], tt[k], a);
        feat[r * FSTR + 172 + o] = a;
      }
    }
  } else if (tid >= 64 && tid < 192) {
    int t = tid - 64;
    int r = t >> 4, o = t & 15;
    float a = c_b2[o];
    const float* hh = h1c + r * 33;
    #pragma unroll
    for (int k = 0; k < 32; k++) a = fmaf(c_w2[o * 32 + k], hh[k], a);
    feat[r * FSTR + 144 + o] = a;
  }
  __syncthreads();

  {
    const int o = tid & 127, rg = tid >> 7;
    const float* f0p = feat + (rg * 4 + 0) * FSTR;
    const float* f1p = feat + (rg * 4 + 1) * FSTR;
    const float* f2p = feat + (rg * 4 + 2) * FSTR;
    const float* f3p = feat + (rg * 4 + 3) * FSTR;
    float a0 = 0.f, a1 = 0.f, a2 = 0.f, a3 = 0.f;
    #pragma unroll 3
    for (int k4 = 0; k4 < 45; k4++) {
      float w0 = C1t[(size_t)(k4 * 4 + 0) * 128 + o];
      float w1 = C1t[(size_t)(k4 * 4 + 1) * 128 + o];
      float w2 = C1t[(size_t)(k4 * 4 + 2) * 128 + o];
      float w3 = C1t[(size_t)(k4 * 4 + 3) * 128 + o];
      float4 f0 = *(const float4*)(f0p + k4 * 4);
      float4 f1 = *(const float4*)(f1p + k4 * 4);
      float4 f2 = *(const float4*)(f2p + k4 * 4);
      float4 f3 = *(const float4*)(f3p + k4 * 4);
      a0 = fmaf(w0, f0.x, a0); a0 = fmaf(w1, f0.y, a0);
      a0 = fmaf(w2, f0.z, a0); a0 = fmaf(w3, f0.w, a0);
      a1 = fmaf(w0, f1.x, a1); a1 = fmaf(w1, f1.y, a1);
      a1 = fmaf(w2, f1.z, a1); a1 = fmaf(w3, f1.w, a1);
      a2 = fmaf(w0, f2.x, a2); a2 = fmaf(w1, f2.y, a2);
      a2 = fmaf(w2, f2.z, a2); a2 = fmaf(w3, f2.w, a2);
      a3 = fmaf(w0, f3.x, a3); a3 = fmaf(w1, f3.y, a3);
      a3 = fmaf(w2, f3.z, a3); a3 = fmaf(w3, f3.w, a3);
    }
    float bb = c1b[o];
    h1[(rg * 4 + 0) * 128 + o] = fmaxf(a0 + bb, 0.f);
    h1[(rg * 4 + 1) * 128 + o] = fmaxf(a1 + bb, 0.f);
    h1[(rg * 4 + 2) * 128 + o] = fmaxf(a2 + bb, 0.f);
    h1[(rg * 4 + 3) * 128 + o] = fmaxf(a3 + bb, 0.f);
  }
  __syncthreads();
  {
    const int o = tid & 63, rg = tid >> 6;
    const float* f0p = h1 + (rg * 2 + 0) * 128;
    const float* f1p = h1 + (rg * 2 + 1) * 128;
    float a0 = 0.f, a1 = 0.f;
    #pragma unroll 4
    for (int k4 = 0; k4 < 32; k4++) {
      float w0 = g_w2t[(k4 * 4 + 0) * 64 + o];
      float w1 = g_w2t[(k4 * 4 + 1) * 64 + o];
      float w2 = g_w2t[(k4 * 4 + 2) * 64 + o];
      float w3 = g_w2t[(k4 * 4 + 3) * 64 + o];
      float4 f0 = *(const float4*)(f0p + k4 * 4);
      float4 f1 = *(const float4*)(f1p + k4 * 4);
      a0 = fmaf(w0, f0.x, a0); a0 = fmaf(w1, f0.y, a0);
      a0 = fmaf(w2, f0.z, a0); a0 = fmaf(w3, f0.w, a0);
      a1 = fmaf(w0, f1.x, a1); a1 = fmaf(w1, f1.y, a1);
      a1 = fmaf(w2, f1.z, a1); a1 = fmaf(w3, f1.w, a1);
    }
    float bb = g_b2[o];
    h2[(rg * 2 + 0) * 64 + o] = fmaxf(a0 + bb, 0.f);
    h2[(rg * 2 + 1) * 64 + o] = fmaxf(a1 + bb, 0.f);
  }
  __syncthreads();
  {
    const int o = tid & 31, rg = tid >> 5;
    const float* fp = h2 + rg * 64;
    float a = 0.f;
    #pragma unroll 4
    for (int k4 = 0; k4 < 16; k4++) {
      float w0 = g_w3t[(k4 * 4 + 0) * 32 + o];
      float w1 = g_w3t[(k4 * 4 + 1) * 32 + o];
      float w2 = g_w3t[(k4 * 4 + 2) * 32 + o];
      float w3 = g_w3t[(k4 * 4 + 3) * 32 + o];
      float4 f0 = *(const float4*)(fp + k4 * 4);
      a = fmaf(w0, f0.x, a); a = fmaf(w1, f0.y, a);
      a = fmaf(w2, f0.z, a); a = fmaf(w3, f0.w, a);
    }
    h3[rg * 32 + o] = fmaxf(a + g_b3[o], 0.f);
  }
  __syncthreads();
  if (tid < 32) {
    int r = tid >> 2, o = tid & 3;
    const float* hh = h3 + r * 32;
    float a = g_b4[o];
    #pragma unroll
    for (int k = 0; k < 32; k++) a = fmaf(g_w4t[k * 4 + o], hh[k], a);
    lg[tid] = a;
  }
  __syncthreads();
  if (tid < 8) {
    float l0 = lg[tid * 4 + 0], l1 = lg[tid * 4 + 1];
    float l2 = lg[tid * 4 + 2], l3 = lg[tid * 4 + 3];
    float m = fmaxf(fmaxf(l0, l1), fmaxf(l2, l3));
    float e0 = __expf(l0 - m), e1 = __expf(l1 - m);
    float e2 = __expf(l2 - m), e3 = __expf(l3 - m);
    float is = __builtin_amdgcn_rcpf(e0 + e1 + e2 + e3);
    float4 o4; o4.x = e0 * is; o4.y = e1 * is; o4.z = e2 * is; o4.w = e3 * is;
    *(float4*)(out + (size_t)(b0 + tid) * 4) = o4;
  }
}

// ---------------------------------------------------------------------------
extern "C" void kernel_launch(void* const* d_in, const int* in_sizes, int n_in,
                              void* d_out, int out_size, void* d_ws, size_t ws_size,
                              hipStream_t stream) {
  const int*   x     = (const int*)d_in[0];
  const float* emb   = (const float*)d_in[1];
  const float* wih_f = (const float*)d_in[2];
  const float* whh_f = (const float*)d_in[3];
  const float* bih_f = (const float*)d_in[4];
  const float* bhh_f = (const float*)d_in[5];
  const float* wih_r = (const float*)d_in[6];
  const float* whh_r = (const float*)d_in[7];
  const float* bih_r = (const float*)d_in[8];
  const float* bhh_r = (const float*)d_in[9];
  const float* e_w1 = (const float*)d_in[10]; const float* e_b1 = (const float*)d_in[11];
  const float* e_w2 = (const float*)d_in[12]; const float* e_b2 = (const float*)d_in[13];
  const float* l_w1 = (const float*)d_in[14]; const float* l_b1 = (const float*)d_in[15];
  const float* l_w2 = (const float*)d_in[16]; const float* l_b2 = (const float*)d_in[17];
  const float* c_w1 = (const float*)d_in[18]; const float* c_b1 = (const float*)d_in[19];
  const float* c_w2 = (const float*)d_in[20]; const float* c_b2 = (const float*)d_in[21];
  const float* p_w1 = (const float*)d_in[22]; const float* p_b1 = (const float*)d_in[23];
  const float* p_w2 = (const float*)d_in[24]; const float* p_b2 = (const float*)d_in[25];
  const float* x_w1 = (const float*)d_in[26]; const float* x_b1 = (const float*)d_in[27];
  const float* x_w2 = (const float*)d_in[28]; const float* x_b2 = (const float*)d_in[29];
  const float* fp_w = (const float*)d_in[30]; const float* fp_b = (const float*)d_in[31];
  const float* attn_w = (const float*)d_in[32]; const float* attn_b = (const float*)d_in[33];
  const float* out_w = (const float*)d_in[34]; const float* out_b = (const float*)d_in[35];
  const float* g_w1 = (const float*)d_in[36]; const float* g_b1 = (const float*)d_in[37];
  const float* g_w2 = (const float*)d_in[38]; const float* g_b2 = (const float*)d_in[39];
  const float* g_w3 = (const float*)d_in[40]; const float* g_b3 = (const float*)d_in[41];
  const float* g_w4 = (const float*)d_in[42]; const float* g_b4 = (const float*)d_in[43];

  float* ws   = (float*)d_ws;
  float* G_f  = ws;                       // 512*256
  float* G_r  = G_f  + 512 * 256;
  float* hfw  = G_r  + 512 * 256;         // B*64
  float* hrw  = hfw  + BATCH * 64;
  float* entw = hrw  + BATCH * 64;        // B
  float* vlnw = entw + BATCH;
  float* patw = vlnw + BATCH;             // B*6
  float* cpxw = patw + BATCH * 6;         // B*4
  float* Aw   = cpxw + BATCH * 4;         // 128*184
  float* avbw = Aw + 128 * ADJ;           // 128
  float* Bpw  = avbw + 128;               // 184*180
  float* vbw  = Bpw + ADJ * 180;          // 184
  float* C1t  = vbw + ADJ;                // 180*128
  float* c1b  = C1t + 180 * 128;          // 128
  float* g2t  = c1b + 128;                // 128*64
  float* g3t  = g2t + 128 * 64;           // 64*32
  float* g4t  = g3t + 64 * 32;            // 32*4
  float* cw1t = g4t + 32 * 4;             // 512*32
  unsigned short* Wfrag = (unsigned short*)(cw1t + 512 * 32);  // 32768 bf16

  k_prep<<<dim3(465), dim3(256), 0, stream>>>(
      emb, wih_f, bih_f, bhh_f, wih_r, bih_r, bhh_r, whh_f, whh_r,
      g_w1, g_b1, out_w, out_b, attn_w, attn_b, fp_w, fp_b,
      g_w2, g_w3, g_w4, c_w1,
      G_f, G_r, Wfrag, Aw, avbw, Bpw, vbw, g2t, g3t, g4t, cw1t);
  k_main<<<dim3(1664), dim3(256), 0, stream>>>(
      x, G_f, G_r, Wfrag, Aw, avbw, Bpw, vbw, C1t, c1b,
      hfw, hrw, entw, vlnw, patw, cpxw);
  k_head<<<dim3(BATCH / 8), dim3(256), 0, stream>>>(
      x, hfw, hrw, entw, vlnw, patw, cpxw,
      e_w1, e_b1, e_w2, e_b2, l_w1, l_b1, l_w2, l_b2,
      cw1t, c_b1, c_w2, c_b2, p_w1, p_b1, p_w2, p_b2,
      x_w1, x_b1, x_w2, x_b2, C1t, c1b,
      g2t, g_b2, g3t, g_b3, g4t, g_b4,
      (float*)d_out);
}